// Round 1
// baseline (152.836 us; speedup 1.0000x reference)
//
#include <hip/hip_runtime.h>
#include <hip/hip_bf16.h>

typedef __attribute__((ext_vector_type(8))) short bf16x8;
typedef __attribute__((ext_vector_type(4))) float f32x4;

#define XP_BYTES 27557888   // 16*58*58*256 * 2B padded NHWC bf16
#define WR_OFF   27557888   // Wr right after Xp in d_ws
#define NT_ITERS 36         // 9 taps * (256/64) c-chunks

// ---------------- weight synthesis: softmax(alphas) + circulant averages ----
__global__ void wsynth_kernel(const float* __restrict__ W,
                              const float* __restrict__ alphas,
                              const float* __restrict__ gumbels,
                              __hip_bfloat16* __restrict__ Wr) {
    int tid = blockIdx.x * 256 + threadIdx.x;   // 65536 threads: one per (o,i)
    int o = tid >> 8, i = tid & 255;

    float a[7]; float mx = -1e30f;
    for (int j = 0; j < 7; ++j) { a[j] = alphas[j] + 1.0e-4f * gumbels[j]; mx = fmaxf(mx, a[j]); }
    float s = 0.f;
    for (int j = 0; j < 7; ++j) { a[j] = __expf(a[j] - mx); s += a[j]; }
    float invs = 1.0f / s;
    for (int j = 0; j < 7; ++j) a[j] *= invs;

    float acc[9];
    const float* w0 = W + ((size_t)(o * 256 + i)) * 9;
    for (int t = 0; t < 9; ++t) acc[t] = a[0] * w0[t];

    for (int idx = 1; idx < 7; ++idx) {
        int b = 1 << idx;
        int r = o & (b - 1), sc = i & (b - 1);
        int d = (sc - r) & (b - 1);
        int qb = o - r, pb = i - sc;
        float sum[9];
        for (int t = 0; t < 9; ++t) sum[t] = 0.f;
        for (int t = 0; t < b; ++t) {
            const float* wp = W + ((size_t)((qb + t) * 256 + pb + ((t + d) & (b - 1)))) * 9;
            #pragma unroll
            for (int tp = 0; tp < 9; ++tp) sum[tp] += wp[tp];
        }
        float sc2 = a[idx] / (float)b;
        for (int tp = 0; tp < 9; ++tp) acc[tp] += sc2 * sum[tp];
    }
    // layout [tap][o][c] so conv A-operand k (=c) is contiguous
    for (int tp = 0; tp < 9; ++tp)
        Wr[((size_t)(tp * 256 + o)) * 256 + i] = __float2bfloat16(acc[tp]);
}

// ---------------- NCHW fp32 -> zero-padded NHWC bf16 [16][58][58][256] ------
__global__ void pad_nhwc_kernel(const float* __restrict__ x,
                                __hip_bfloat16* __restrict__ Xp) {
    __shared__ float t[64][65];
    int p0 = blockIdx.x * 64;       // pixel chunk within image (3136/64 = 49)
    int c0 = blockIdx.y * 64;       // channel chunk
    int b  = blockIdx.z;            // image
    int lane = threadIdx.x & 63;
    int grp  = threadIdx.x >> 6;    // 0..3

    const float* src = x + ((size_t)(b * 256 + c0)) * 3136 + p0;
    #pragma unroll
    for (int it = 0; it < 16; ++it) {
        int c = it * 4 + grp;
        t[c][lane] = src[(size_t)c * 3136 + lane];   // coalesced reads
    }
    __syncthreads();
    #pragma unroll
    for (int it = 0; it < 16; ++it) {
        int pl = it * 4 + grp;
        int P = p0 + pl;
        int y = P / 56, xx = P - y * 56;
        Xp[(((size_t)(b * 58 + y + 1)) * 58 + (xx + 1)) * 256 + c0 + lane] =
            __float2bfloat16(t[lane][pl]);           // coalesced 128B writes
    }
}

// ---------------- implicit-GEMM conv: 128x128 tile, BK=64, bf16 MFMA --------
__device__ __forceinline__ void gload16(const __hip_bfloat16* g, __hip_bfloat16* l) {
    __builtin_amdgcn_global_load_lds(
        (const __attribute__((address_space(1))) void*)g,
        (__attribute__((address_space(3))) void*)l, 16, 0, 0);
}

__global__ __launch_bounds__(256, 2) void conv_kernel(
        const __hip_bfloat16* __restrict__ Xp,
        const __hip_bfloat16* __restrict__ Wr,
        float* __restrict__ out) {
    __shared__ __hip_bfloat16 Xs[2][128][64];   // [pixel][k] per buffer
    __shared__ __hip_bfloat16 Ws[2][128][64];   // [och][k]  per buffer

    int bid = blockIdx.x;
    int n0 = (bid & 1) * 128;          // out-channel tile (N=256 -> 2 tiles)
    int m0 = (bid >> 1) * 128;         // pixel tile (50176/128 = 392)
    int tid = threadIdx.x;
    int col8 = (tid & 7) * 8;          // k sub-offset for staging
    int rowq = tid >> 3;               // 0..31 row per staging round
    int w = tid >> 6;                  // wave 0..3
    int lane = tid & 63;
    int l15 = lane & 15;
    int koff = (lane >> 4) * 8;        // frag k offset

    // per-round pixel base addresses into padded NHWC (elements)
    int apix[4], bwt[4];
    #pragma unroll
    for (int r = 0; r < 4; ++r) {
        int m = r * 32 + rowq;
        int P = m0 + m;
        int bb = P / 3136;
        int rem = P - bb * 3136;
        int y = rem / 56;
        int xx = rem - y * 56;
        apix[r] = (((bb * 58) + y + 1) * 58 + (xx + 1)) * 256 + col8;
        bwt[r]  = (n0 + m) * 256 + col8;
    }
    int ldsw = w * 512;                // wave-uniform LDS element offset

    f32x4 acc[4][4] = {};

    int wn = (w >> 1) * 64;            // wave's out-channel half
    int wm = (w & 1) * 64;             // wave's pixel half

    auto stage = [&](int buf, int kk) {
        int tap = kk >> 2;
        int kc  = (kk & 3) * 64;
        int dy = tap / 3 - 1, dx = tap - (tap / 3) * 3 - 1;
        int xoff = (dy * 58 + dx) * 256 + kc;   // tap shift in padded NHWC
        int woff = tap * 65536 + kc;
        #pragma unroll
        for (int r = 0; r < 4; ++r) {
            gload16(Xp + apix[r] + xoff, &Xs[buf][0][0] + r * 2048 + ldsw);
            gload16(Wr + bwt[r]  + woff, &Ws[buf][0][0] + r * 2048 + ldsw);
        }
    };

    stage(0, 0);
    __syncthreads();

    int cur = 0;
    for (int kk = 0; kk < NT_ITERS; ++kk) {
        if (kk + 1 < NT_ITERS) stage(cur ^ 1, kk + 1);
        #pragma unroll
        for (int ks = 0; ks < 2; ++ks) {
            int ko = ks * 32 + koff;
            bf16x8 af[4], bfr[4];
            #pragma unroll
            for (int nf = 0; nf < 4; ++nf)
                af[nf] = *(const bf16x8*)(&Ws[cur][wn + nf * 16 + l15][ko]);
            #pragma unroll
            for (int mf = 0; mf < 4; ++mf)
                bfr[mf] = *(const bf16x8*)(&Xs[cur][wm + mf * 16 + l15][ko]);
            #pragma unroll
            for (int nf = 0; nf < 4; ++nf)
                #pragma unroll
                for (int mf = 0; mf < 4; ++mf)
                    acc[nf][mf] = __builtin_amdgcn_mfma_f32_16x16x32_bf16(
                        af[nf], bfr[mf], acc[nf][mf], 0, 0, 0);
        }
        __syncthreads();   // drains vmcnt (prefetch) + lgkm, all waves
        cur ^= 1;
    }

    // epilogue: D row = out-channel, col = pixel -> contiguous 64B runs
    int Pd[4], Pm[4];
    #pragma unroll
    for (int mf = 0; mf < 4; ++mf) {
        int P = m0 + wm + mf * 16 + l15;
        Pd[mf] = P / 3136;
        Pm[mf] = P - Pd[mf] * 3136;
    }
    int nbase = n0 + wn + (lane >> 4) * 4;
    #pragma unroll
    for (int nf = 0; nf < 4; ++nf) {
        #pragma unroll
        for (int mf = 0; mf < 4; ++mf) {
            f32x4 v = acc[nf][mf];
            int n = nbase + nf * 16;
            #pragma unroll
            for (int rr = 0; rr < 4; ++rr)
                out[((size_t)(Pd[mf] * 256 + n + rr)) * 3136 + Pm[mf]] = v[rr];
        }
    }
}

extern "C" void kernel_launch(void* const* d_in, const int* in_sizes, int n_in,
                              void* d_out, int out_size, void* d_ws, size_t ws_size,
                              hipStream_t stream) {
    const float* x       = (const float*)d_in[0];
    const float* weight  = (const float*)d_in[1];
    const float* alphas  = (const float*)d_in[2];
    const float* gumbels = (const float*)d_in[3];
    float* out = (float*)d_out;

    __hip_bfloat16* Xp = (__hip_bfloat16*)d_ws;
    __hip_bfloat16* Wr = (__hip_bfloat16*)((char*)d_ws + WR_OFF);

    hipMemsetAsync(Xp, 0, (size_t)XP_BYTES, stream);  // zero pad border (whole buf)
    hipLaunchKernelGGL(wsynth_kernel,   dim3(256),        dim3(256), 0, stream,
                       weight, alphas, gumbels, Wr);
    hipLaunchKernelGGL(pad_nhwc_kernel, dim3(49, 4, 16),  dim3(256), 0, stream,
                       x, Xp);
    hipLaunchKernelGGL(conv_kernel,     dim3(784),        dim3(256), 0, stream,
                       Xp, Wr, out);
}

// Round 2
// 133.092 us; speedup vs baseline: 1.1484x; 1.1484x over previous
//
#include <hip/hip_runtime.h>
#include <hip/hip_bf16.h>

typedef __attribute__((ext_vector_type(8))) short bf16x8;
typedef __attribute__((ext_vector_type(4))) float f32x4;

#define WR_OFF   27557888   // Wr right after Xp (16*58*58*256*2B) in d_ws

// ---------------- weight synthesis: softmax(alphas) + circulant averages ----
__global__ void wsynth_kernel(const float* __restrict__ W,
                              const float* __restrict__ alphas,
                              const float* __restrict__ gumbels,
                              __hip_bfloat16* __restrict__ Wr) {
    int tid = blockIdx.x * 256 + threadIdx.x;   // 65536 threads: one per (o,i)
    int o = tid >> 8, i = tid & 255;

    float a[7]; float mx = -1e30f;
    for (int j = 0; j < 7; ++j) { a[j] = alphas[j] + 1.0e-4f * gumbels[j]; mx = fmaxf(mx, a[j]); }
    float s = 0.f;
    for (int j = 0; j < 7; ++j) { a[j] = __expf(a[j] - mx); s += a[j]; }
    float invs = 1.0f / s;
    for (int j = 0; j < 7; ++j) a[j] *= invs;

    float acc[9];
    const float* w0 = W + ((size_t)(o * 256 + i)) * 9;
    for (int t = 0; t < 9; ++t) acc[t] = a[0] * w0[t];

    for (int idx = 1; idx < 7; ++idx) {
        int b = 1 << idx;
        int r = o & (b - 1), sc = i & (b - 1);
        int d = (sc - r) & (b - 1);
        int qb = o - r, pb = i - sc;
        float sum[9];
        for (int t = 0; t < 9; ++t) sum[t] = 0.f;
        for (int t = 0; t < b; ++t) {
            const float* wp = W + ((size_t)((qb + t) * 256 + pb + ((t + d) & (b - 1)))) * 9;
            #pragma unroll
            for (int tp = 0; tp < 9; ++tp) sum[tp] += wp[tp];
        }
        float sc2 = a[idx] / (float)b;
        for (int tp = 0; tp < 9; ++tp) acc[tp] += sc2 * sum[tp];
    }
    // layout [tap][o][c] so conv A-operand k (=c) is contiguous
    for (int tp = 0; tp < 9; ++tp)
        Wr[((size_t)(tp * 256 + o)) * 256 + i] = __float2bfloat16(acc[tp]);
}

// ---------------- zero only the pad frame of Xp [16][58][58][256] -----------
__global__ void zero_border_kernel(__hip_bfloat16* __restrict__ Xp) {
    int t = blockIdx.x * 256 + threadIdx.x;   // 16*228*256 = 933888 exactly
    int c = t & 255;
    int pp = t >> 8;
    int b = pp / 228;
    int p = pp - b * 228;
    int y, x;
    if (p < 58)       { y = 0;            x = p; }
    else if (p < 116) { y = 57;           x = p - 58; }
    else if (p < 172) { y = 1 + (p - 116); x = 0; }
    else              { y = 1 + (p - 172); x = 57; }
    Xp[((size_t)(b * 58 + y) * 58 + x) * 256 + c] = __float2bfloat16(0.f);
}

// ---------------- NCHW fp32 -> zero-padded NHWC bf16 [16][58][58][256] ------
__global__ void pad_nhwc_kernel(const float* __restrict__ x,
                                __hip_bfloat16* __restrict__ Xp) {
    __shared__ float t[64][65];
    int p0 = blockIdx.x * 64;       // pixel chunk within image (3136/64 = 49)
    int c0 = blockIdx.y * 64;       // channel chunk
    int b  = blockIdx.z;            // image
    int lane = threadIdx.x & 63;
    int grp  = threadIdx.x >> 6;    // 0..3

    const float* src = x + ((size_t)(b * 256 + c0)) * 3136 + p0;
    #pragma unroll
    for (int it = 0; it < 16; ++it) {
        int c = it * 4 + grp;
        t[c][lane] = src[(size_t)c * 3136 + lane];   // coalesced reads
    }
    __syncthreads();
    #pragma unroll
    for (int it = 0; it < 16; ++it) {
        int pl = it * 4 + grp;
        int P = p0 + pl;
        int y = P / 56, xx = P - y * 56;
        Xp[(((size_t)(b * 58 + y + 1)) * 58 + (xx + 1)) * 256 + c0 + lane] =
            __float2bfloat16(t[lane][pl]);           // coalesced 128B writes
    }
}

// ---------------- conv: 256x256 tile, BK=32, triple-buffer, counted vmcnt ---
__device__ __forceinline__ void gload16(const __hip_bfloat16* g, char* l) {
    __builtin_amdgcn_global_load_lds(
        (const __attribute__((address_space(1))) void*)g,
        (__attribute__((address_space(3))) void*)l, 16, 0, 0);
}

__device__ __forceinline__ void stage_pair(const __hip_bfloat16* src, char* dst) {
    gload16(src,      dst);          // k-slots 0-1 (512 thr x 16B = 8KB)
    gload16(src + 16, dst + 8192);   // k-slots 2-3
}

// One K-step (BK=32): 2 phases x {ds_read, stage-issue, barrier, lgkm, 16 MFMA, barrier}
template<int VM, bool DOSTAGE>
__device__ __forceinline__ void conv_step(
        int kk, char* smem, int cur, int st, int w,
        const int (&aOff)[4], const int (&bOff)[8],
        const __hip_bfloat16* aSrc, const __hip_bfloat16* xSrc,
        f32x4 (&acc)[4][8])
{
    const char* base = smem + cur * 32768;
    bf16x8 af[4], bfr[4];
    // ---- phase 0: A frags + B frags (pixel half 0) ----
    #pragma unroll
    for (int nf = 0; nf < 4; ++nf) af[nf] = *(const bf16x8*)(base + aOff[nf]);
    #pragma unroll
    for (int mf = 0; mf < 4; ++mf) bfr[mf] = *(const bf16x8*)(base + bOff[mf]);
    if constexpr (DOSTAGE) {
        int k2 = kk + 2;
        int tap = k2 >> 3;
        int c0 = (k2 & 7) << 5;
        stage_pair(aSrc + tap * 65536 + c0, smem + st * 32768 + w * 1024);
    }
    __builtin_amdgcn_s_barrier();
    asm volatile("s_waitcnt lgkmcnt(0)" ::: "memory");
    __builtin_amdgcn_s_setprio(1);
    #pragma unroll
    for (int nf = 0; nf < 4; ++nf)
        #pragma unroll
        for (int mf = 0; mf < 4; ++mf)
            acc[nf][mf] = __builtin_amdgcn_mfma_f32_16x16x32_bf16(af[nf], bfr[mf], acc[nf][mf], 0, 0, 0);
    __builtin_amdgcn_s_setprio(0);
    __builtin_amdgcn_s_barrier();

    // ---- phase 1: B frags (pixel half 1) ----
    #pragma unroll
    for (int mf = 0; mf < 4; ++mf) bfr[mf] = *(const bf16x8*)(base + bOff[4 + mf]);
    if constexpr (DOSTAGE) {
        int k2 = kk + 2;
        int tap = k2 >> 3;
        int ty = (tap >= 6) ? 2 : ((tap >= 3) ? 1 : 0);
        int txo = ((ty - 1) * 58 + (tap - ty * 3 - 1)) * 256;
        int c0 = (k2 & 7) << 5;
        stage_pair(xSrc + txo + c0, smem + st * 32768 + 16384 + w * 1024);
    }
    // gate for step kk+1's data: drain its 4 gloads, keep kk+2's 4 in flight.
    // vmcnt BEFORE a barrier => after the barrier, ALL waves' older loads landed.
    if constexpr (VM == 4)      asm volatile("s_waitcnt vmcnt(4)" ::: "memory");
    else if constexpr (VM == 0) asm volatile("s_waitcnt vmcnt(0)" ::: "memory");
    __builtin_amdgcn_s_barrier();
    asm volatile("s_waitcnt lgkmcnt(0)" ::: "memory");
    __builtin_amdgcn_s_setprio(1);
    #pragma unroll
    for (int nf = 0; nf < 4; ++nf)
        #pragma unroll
        for (int mf = 0; mf < 4; ++mf)
            acc[nf][4 + mf] = __builtin_amdgcn_mfma_f32_16x16x32_bf16(af[nf], bfr[mf], acc[nf][4 + mf], 0, 0, 0);
    __builtin_amdgcn_s_setprio(0);
    __builtin_amdgcn_s_barrier();
}

__global__ __launch_bounds__(512, 2) void conv_kernel(
        const __hip_bfloat16* __restrict__ Xp,
        const __hip_bfloat16* __restrict__ Wr,
        float* __restrict__ out) {
    extern __shared__ char smem[];   // 3 bufs x (A 16KB [4 slot][256 och][8] + X 16KB)

    const int tid = threadIdx.x;
    const int w = tid >> 6;          // wave 0..7
    const int lane = tid & 63;
    const int l15 = lane & 15;
    const int q = lane >> 4;         // k-slot of MFMA frag
    const int m0 = blockIdx.x << 8;  // 256-pixel tile (196 blocks)

    const int wn = (w & 3) << 6;     // wave och base (4 waves x 64)
    const int wm = (w >> 2) << 7;    // wave pixel base (2 waves x 128)

    // staging constants: thread t -> row (t&255), k-slot-half (t>>8)
    const int srow = tid & 255;
    const int shalf = tid >> 8;
    const __hip_bfloat16* aSrc = Wr + srow * 256 + shalf * 8;
    int P = m0 + srow;
    int bb = P / 3136;
    int rem = P - bb * 3136;
    int y = rem / 56;
    int xx = rem - y * 56;
    const __hip_bfloat16* xSrc = Xp + ((size_t)((bb * 58) + y + 1) * 58 + (xx + 1)) * 256 + shalf * 8;

    // LDS frag read offsets (bytes): [slot][row][8 bf16] => conflict-free
    int aOff[4], bOff[8];
    #pragma unroll
    for (int nf = 0; nf < 4; ++nf) aOff[nf] = q * 4096 + (wn + nf * 16 + l15) * 16;
    #pragma unroll
    for (int mf = 0; mf < 8; ++mf) bOff[mf] = 16384 + q * 4096 + (wm + mf * 16 + l15) * 16;

    f32x4 acc[4][8];
    #pragma unroll
    for (int a1 = 0; a1 < 4; ++a1)
        #pragma unroll
        for (int a2 = 0; a2 < 8; ++a2)
            acc[a1][a2] = (f32x4){0.f, 0.f, 0.f, 0.f};

    // prologue: stage steps 0,1 then gate step 0
    {
        stage_pair(aSrc, smem + w * 1024);                         // kk=0: tap0,c0=0
        stage_pair(xSrc - 15104, smem + 16384 + w * 1024);         // txo=(-59)*256
        stage_pair(aSrc + 32, smem + 32768 + w * 1024);            // kk=1: c0=32
        stage_pair(xSrc - 15104 + 32, smem + 32768 + 16384 + w * 1024);
    }
    asm volatile("s_waitcnt vmcnt(4)" ::: "memory");
    __builtin_amdgcn_s_barrier();

    int cur = 0;
    for (int kk = 0; kk < 70; ++kk) {
        int st = (cur >= 1) ? cur - 1 : 2;      // (cur+2)%3
        conv_step<4, true>(kk, smem, cur, st, w, aOff, bOff, aSrc, xSrc, acc);
        cur = (cur == 2) ? 0 : cur + 1;
    }
    conv_step<0,  false>(70, smem, 1, 0, w, aOff, bOff, aSrc, xSrc, acc);
    conv_step<-1, false>(71, smem, 2, 0, w, aOff, bOff, aSrc, xSrc, acc);

    // epilogue: D row = och (via q,reg), col = pixel (l15) -> 64B runs
    const int nb = wn + q * 4;
    #pragma unroll
    for (int mf = 0; mf < 8; ++mf) {
        int P2 = m0 + wm + mf * 16 + l15;
        int pd = P2 / 3136;
        int pm = P2 - pd * 3136;
        size_t ob = (size_t)pd * 256 * 3136 + pm;
        #pragma unroll
        for (int nf = 0; nf < 4; ++nf) {
            #pragma unroll
            for (int rr = 0; rr < 4; ++rr)
                out[ob + (size_t)(nb + nf * 16 + rr) * 3136] = acc[nf][mf][rr];
        }
    }
}

extern "C" void kernel_launch(void* const* d_in, const int* in_sizes, int n_in,
                              void* d_out, int out_size, void* d_ws, size_t ws_size,
                              hipStream_t stream) {
    const float* x       = (const float*)d_in[0];
    const float* weight  = (const float*)d_in[1];
    const float* alphas  = (const float*)d_in[2];
    const float* gumbels = (const float*)d_in[3];
    float* out = (float*)d_out;

    __hip_bfloat16* Xp = (__hip_bfloat16*)d_ws;
    __hip_bfloat16* Wr = (__hip_bfloat16*)((char*)d_ws + WR_OFF);

    hipFuncSetAttribute(reinterpret_cast<const void*>(conv_kernel),
                        hipFuncAttributeMaxDynamicSharedMemorySize, 98304);

    hipLaunchKernelGGL(zero_border_kernel, dim3(3648),      dim3(256), 0, stream, Xp);
    hipLaunchKernelGGL(wsynth_kernel,      dim3(256),       dim3(256), 0, stream,
                       weight, alphas, gumbels, Wr);
    hipLaunchKernelGGL(pad_nhwc_kernel,    dim3(49, 4, 16), dim3(256), 0, stream, x, Xp);
    hipLaunchKernelGGL(conv_kernel,        dim3(196),       dim3(512), 98304, stream,
                       Xp, Wr, out);
}

// Round 3
// 110.715 us; speedup vs baseline: 1.3804x; 1.2021x over previous
//
#include <hip/hip_runtime.h>
#include <hip/hip_bf16.h>

typedef __attribute__((ext_vector_type(8))) short bf16x8;
typedef __attribute__((ext_vector_type(4))) float f32x4;

#define WR_OFF   27557888   // Wr right after Xp (16*58*58*256*2B) in d_ws

// conv LDS map (dynamic, 114688 B total):
#define XBAND_SZ 24576      // [slot4][row6][x64][16B] per band buffer
#define WBUF_OFF 49152      // after 2 X bands
#define WBUF_SZ  16384      // [slot4][och256][16B] per W buffer (x4)

// ---------------- weight synthesis: softmax(alphas) + circulant averages ----
__global__ void wsynth_kernel(const float* __restrict__ W,
                              const float* __restrict__ alphas,
                              const float* __restrict__ gumbels,
                              __hip_bfloat16* __restrict__ Wr) {
    int tid = blockIdx.x * 256 + threadIdx.x;   // 65536 threads: one per (o,i)
    int o = tid >> 8, i = tid & 255;

    float a[7]; float mx = -1e30f;
    for (int j = 0; j < 7; ++j) { a[j] = alphas[j] + 1.0e-4f * gumbels[j]; mx = fmaxf(mx, a[j]); }
    float s = 0.f;
    for (int j = 0; j < 7; ++j) { a[j] = __expf(a[j] - mx); s += a[j]; }
    float invs = 1.0f / s;
    for (int j = 0; j < 7; ++j) a[j] *= invs;

    float acc[9];
    const float* w0 = W + ((size_t)(o * 256 + i)) * 9;
    for (int t = 0; t < 9; ++t) acc[t] = a[0] * w0[t];

    for (int idx = 1; idx < 7; ++idx) {
        int b = 1 << idx;
        int r = o & (b - 1), sc = i & (b - 1);
        int d = (sc - r) & (b - 1);
        int qb = o - r, pb = i - sc;
        float sum[9];
        for (int t = 0; t < 9; ++t) sum[t] = 0.f;
        for (int t = 0; t < b; ++t) {
            const float* wp = W + ((size_t)((qb + t) * 256 + pb + ((t + d) & (b - 1)))) * 9;
            #pragma unroll
            for (int tp = 0; tp < 9; ++tp) sum[tp] += wp[tp];
        }
        float sc2 = a[idx] / (float)b;
        for (int tp = 0; tp < 9; ++tp) acc[tp] += sc2 * sum[tp];
    }
    // layout [tap][o][c] so conv A-operand k (=c) is contiguous
    for (int tp = 0; tp < 9; ++tp)
        Wr[((size_t)(tp * 256 + o)) * 256 + i] = __float2bfloat16(acc[tp]);
}

// ---------------- zero only the pad frame of Xp [16][58][58][256] -----------
__global__ void zero_border_kernel(__hip_bfloat16* __restrict__ Xp) {
    int t = blockIdx.x * 256 + threadIdx.x;   // 16*228*256 = 933888 exactly
    int c = t & 255;
    int pp = t >> 8;
    int b = pp / 228;
    int p = pp - b * 228;
    int y, x;
    if (p < 58)       { y = 0;            x = p; }
    else if (p < 116) { y = 57;           x = p - 58; }
    else if (p < 172) { y = 1 + (p - 116); x = 0; }
    else              { y = 1 + (p - 172); x = 57; }
    Xp[((size_t)(b * 58 + y) * 58 + x) * 256 + c] = __float2bfloat16(0.f);
}

// ---------------- NCHW fp32 -> zero-padded NHWC bf16 [16][58][58][256] ------
__global__ void pad_nhwc_kernel(const float* __restrict__ x,
                                __hip_bfloat16* __restrict__ Xp) {
    __shared__ float t[64][65];
    int p0 = blockIdx.x * 64;       // pixel chunk within image (3136/64 = 49)
    int c0 = blockIdx.y * 64;       // channel chunk
    int b  = blockIdx.z;            // image
    int lane = threadIdx.x & 63;
    int grp  = threadIdx.x >> 6;    // 0..3

    const float* src = x + ((size_t)(b * 256 + c0)) * 3136 + p0;
    #pragma unroll
    for (int it = 0; it < 16; ++it) {
        int c = it * 4 + grp;
        t[c][lane] = src[(size_t)c * 3136 + lane];   // coalesced reads
    }
    __syncthreads();
    #pragma unroll
    for (int it = 0; it < 16; ++it) {
        int pl = it * 4 + grp;
        int P = p0 + pl;
        int y = P / 56, xx = P - y * 56;
        Xp[(((size_t)(b * 58 + y + 1)) * 58 + (xx + 1)) * 256 + c0 + lane] =
            __float2bfloat16(t[lane][pl]);           // coalesced 128B writes
    }
}

// ---------------- conv: 224x256 tile, tap-banded X, quad-buffered W ---------
__device__ __forceinline__ void gload16(const __hip_bfloat16* g, char* l) {
    __builtin_amdgcn_global_load_lds(
        (const __attribute__((address_space(1))) void*)g,
        (__attribute__((address_space(3))) void*)l, 16, 0, 0);
}

template<int N> __device__ __forceinline__ void gate() {
    if constexpr (N == 0) asm volatile("s_waitcnt vmcnt(0)" ::: "memory");
    else if constexpr (N == 2) asm volatile("s_waitcnt vmcnt(2)" ::: "memory");
    else if constexpr (N == 4) asm volatile("s_waitcnt vmcnt(4)" ::: "memory");
    else if constexpr (N == 7) asm volatile("s_waitcnt vmcnt(7)" ::: "memory");
}

// One c-chunk: 9 tap-steps, fully unrolled so tap deltas fold into ds offsets.
template<bool LAST>
__device__ __forceinline__ void chunk_body(
        char* smem, int cc,
        const int (&aOff)[4], const int (&bOff)[7],
        const __hip_bfloat16* wSrc0, const __hip_bfloat16* const (&xSrc)[3],
        int tid, f32x4 (&acc)[4][7])
{
    #pragma unroll
    for (int r = 0; r < 9; ++r) {
        const char* wb = smem + WBUF_OFF + ((cc + r) & 3) * WBUF_SZ;
        const char* xb = smem + (cc & 1) * XBAND_SZ;
        const int dy = r / 3 - 1, dx = r - (r / 3) * 3 - 1;
        const int timm = (dy * 64 + dx) * 16 + 1040;  // tap delta, bias +1040

        bf16x8 af[4], bf[4];
        #pragma unroll
        for (int nf = 0; nf < 4; ++nf) af[nf] = *(const bf16x8*)(wb + aOff[nf]);
        #pragma unroll
        for (int mf = 0; mf < 4; ++mf) bf[mf] = *(const bf16x8*)(xb + bOff[mf] + timm);

        // stage W for step s+3 (quad buffer)
        if (!LAST || r < 6) {
            const int tap2 = (r + 3 < 9) ? r + 3 : r - 6;
            const int cc2  = (r + 3 < 9) ? cc : cc + 1;
            const __hip_bfloat16* s = wSrc0 + tap2 * 65536 + cc2 * 32;
            char* d = smem + WBUF_OFF + ((cc + r + 3) & 3) * WBUF_SZ + tid * 16;
            gload16(s, d);
            gload16(s + 16, d + 8192);
        }

        __builtin_amdgcn_s_barrier();
        asm volatile("s_waitcnt lgkmcnt(0)" ::: "memory");
        __builtin_amdgcn_s_setprio(1);
        #pragma unroll
        for (int nf = 0; nf < 4; ++nf)
            #pragma unroll
            for (int mf = 0; mf < 4; ++mf)
                acc[nf][mf] = __builtin_amdgcn_mfma_f32_16x16x32_bf16(
                    af[nf], bf[mf], acc[nf][mf], 0, 0, 0);
        __builtin_amdgcn_s_setprio(0);
        __builtin_amdgcn_s_barrier();

        // phase 1: remaining 3 pixel frags
        bf16x8 bg[3];
        #pragma unroll
        for (int mf = 0; mf < 3; ++mf) bg[mf] = *(const bf16x8*)(xb + bOff[4 + mf] + timm);

        if (!LAST && r == 3) {   // stage next c-chunk's X band (3 gloads, ~5.5 steps slack)
            char* d = smem + ((cc + 1) & 1) * XBAND_SZ + tid * 16;
            #pragma unroll
            for (int it = 0; it < 3; ++it)
                gload16(xSrc[it] + (cc + 1) * 32, d + it * 8192);
        }

        // counted gate for NEXT step's W (and band hand-off); never 0 mid-loop
        if constexpr (LAST) {
            if (r < 6) gate<4>();
            else if (r == 6) gate<2>();
            else if (r == 7) gate<0>();
        } else {
            if (r == 3 || r == 4 || r == 5) gate<7>();  // keep X band + 2 W steps in flight
            else gate<4>();
        }
        __builtin_amdgcn_s_barrier();
        asm volatile("s_waitcnt lgkmcnt(0)" ::: "memory");
        __builtin_amdgcn_s_setprio(1);
        #pragma unroll
        for (int nf = 0; nf < 4; ++nf)
            #pragma unroll
            for (int mf = 0; mf < 3; ++mf)
                acc[nf][4 + mf] = __builtin_amdgcn_mfma_f32_16x16x32_bf16(
                    af[nf], bg[mf], acc[nf][4 + mf], 0, 0, 0);
        __builtin_amdgcn_s_setprio(0);
        __builtin_amdgcn_s_barrier();
    }
}

__global__ __launch_bounds__(512, 2) void conv_kernel(
        const __hip_bfloat16* __restrict__ Xp,
        const __hip_bfloat16* __restrict__ Wr,
        float* __restrict__ out) {
    extern __shared__ char smem[];

    const int tid = threadIdx.x;
    const int w = tid >> 6, lane = tid & 63, l15 = lane & 15, q = lane >> 4;
    const int bid = blockIdx.x;            // 224 blocks: 14 per image
    const int bimg = bid / 14;
    const int y0 = (bid - bimg * 14) * 4;  // first image row of 4-row tile

    const int wn = (w & 3) << 6;           // wave och base (4 waves x 64)
    const int wm = (w >> 2) * 112;         // wave pixel base (2 waves x 112)

    // W staging: thread -> (och = tid&255, slots tid>>8 and +2); dest = tid*16 (+8192)
    const __hip_bfloat16* wSrc0 = Wr + (tid & 255) * 256 + (tid >> 8) * 8;

    // X band staging: 3 chunks/thread; chunk = tid + it*512 -> (slot, row, xcol)
    const __hip_bfloat16* xSrc[3];
    #pragma unroll
    for (int it = 0; it < 3; ++it) {
        int chunk = tid + it * 512;
        int slot = chunk / 384;
        int rem  = chunk - slot * 384;
        int row = rem >> 6, xcol = rem & 63;   // xcol>=58 reads in-bounds garbage (unused)
        xSrc[it] = Xp + (((size_t)(bimg * 58 + y0 + row)) * 58 + xcol) * 256 + slot * 8;
    }

    // frag read offsets (bytes)
    int aOff[4];
    #pragma unroll
    for (int nf = 0; nf < 4; ++nf) aOff[nf] = q * 4096 + (wn + nf * 16 + l15) * 16;
    int bOff[7];
    #pragma unroll
    for (int mf = 0; mf < 7; ++mf) {
        int p = wm + mf * 16 + l15;            // local pixel 0..223
        int y = p / 56, x = p - y * 56;
        bOff[mf] = q * 6144 + ((y + 1) * 64 + (x + 1)) * 16 - 1040;
    }

    f32x4 acc[4][7];
    #pragma unroll
    for (int a1 = 0; a1 < 4; ++a1)
        #pragma unroll
        for (int a2 = 0; a2 < 7; ++a2)
            acc[a1][a2] = (f32x4){0.f, 0.f, 0.f, 0.f};

    // prologue: X band 0 first (oldest), then W taps 0,1,2 of chunk 0
    {
        char* d = smem + tid * 16;
        #pragma unroll
        for (int it = 0; it < 3; ++it) gload16(xSrc[it], d + it * 8192);
        #pragma unroll
        for (int t = 0; t < 3; ++t) {
            const __hip_bfloat16* s = wSrc0 + t * 65536;
            char* dw = smem + WBUF_OFF + t * WBUF_SZ + tid * 16;
            gload16(s, dw);
            gload16(s + 16, dw + 8192);
        }
    }
    gate<4>();   // drain band0 + W0; keep W1,W2 in flight
    __builtin_amdgcn_s_barrier();

    for (int cc = 0; cc < 7; ++cc)
        chunk_body<false>(smem, cc, aOff, bOff, wSrc0, xSrc, tid, acc);
    chunk_body<true>(smem, 7, aOff, bOff, wSrc0, xSrc, tid, acc);

    // epilogue: och from (q,nf,rr), pixel from (wm,mf,l15); all in image bimg
    const int nb = wn + q * 4;
    const size_t obB = (size_t)bimg * 256 * 3136;
    #pragma unroll
    for (int mf = 0; mf < 7; ++mf) {
        int pm = y0 * 56 + wm + mf * 16 + l15;
        #pragma unroll
        for (int nf = 0; nf < 4; ++nf) {
            #pragma unroll
            for (int rr = 0; rr < 4; ++rr)
                out[obB + (size_t)(nb + nf * 16 + rr) * 3136 + pm] = acc[nf][mf][rr];
        }
    }
}

extern "C" void kernel_launch(void* const* d_in, const int* in_sizes, int n_in,
                              void* d_out, int out_size, void* d_ws, size_t ws_size,
                              hipStream_t stream) {
    const float* x       = (const float*)d_in[0];
    const float* weight  = (const float*)d_in[1];
    const float* alphas  = (const float*)d_in[2];
    const float* gumbels = (const float*)d_in[3];
    float* out = (float*)d_out;

    __hip_bfloat16* Xp = (__hip_bfloat16*)d_ws;
    __hip_bfloat16* Wr = (__hip_bfloat16*)((char*)d_ws + WR_OFF);

    hipFuncSetAttribute(reinterpret_cast<const void*>(conv_kernel),
                        hipFuncAttributeMaxDynamicSharedMemorySize, 114688);

    hipLaunchKernelGGL(zero_border_kernel, dim3(3648),      dim3(256), 0, stream, Xp);
    hipLaunchKernelGGL(wsynth_kernel,      dim3(256),       dim3(256), 0, stream,
                       weight, alphas, gumbels, Wr);
    hipLaunchKernelGGL(pad_nhwc_kernel,    dim3(49, 4, 16), dim3(256), 0, stream, x, Xp);
    hipLaunchKernelGGL(conv_kernel,        dim3(224),       dim3(512), 114688, stream,
                       Xp, Wr, out);
}